// Round 1
// baseline (1334.176 us; speedup 1.0000x reference)
//
#include <hip/hip_runtime.h>
#include <hip/hip_bf16.h>

typedef short bf16x8 __attribute__((ext_vector_type(8)));
typedef float f32x4 __attribute__((ext_vector_type(4)));
typedef unsigned short u16;
typedef unsigned int u32;

__device__ __forceinline__ u16 f2bf(float f) {
  unsigned u = __float_as_uint(f);
  u += 0x7FFFu + ((u >> 16) & 1u);
  return (u16)(u >> 16);
}

__device__ __forceinline__ void cp16(const u16* g, u16* l) {
  __builtin_amdgcn_global_load_lds((const __attribute__((address_space(1))) u32*)(const void*)g,
                                   (__attribute__((address_space(3))) u32*)(void*)l, 16, 0, 0);
}

// ---------------- prep: cast x to bf16 ----------------
__global__ void cast_x_kernel(const float4* __restrict__ x, ushort4* __restrict__ xb, int n4) {
  int stride = gridDim.x * blockDim.x;
  for (int i = blockIdx.x * blockDim.x + threadIdx.x; i < n4; i += stride) {
    float4 v = x[i];
    ushort4 o;
    o.x = f2bf(v.x); o.y = f2bf(v.y); o.z = f2bf(v.z); o.w = f2bf(v.w);
    xb[i] = o;
  }
}

// ---------------- prep: weights permute+cast, vt pad zero ----------------
// qkv_w rows: o = h*96 + d*3 + t  (reference reshape (h,dh,3))
// permuted rows: o' = t*384 + h*32 + d
__global__ void prep_kernel(const float* __restrict__ qkv_w, const float* __restrict__ qkv_b,
                            const float* __restrict__ out_w,
                            u16* __restrict__ qkv_wp, float* __restrict__ qkv_bp,
                            u16* __restrict__ out_wb, u16* __restrict__ vt, int Bwin) {
  int stride = gridDim.x * blockDim.x;
  int tid0 = blockIdx.x * blockDim.x + threadIdx.x;
  for (int i = tid0; i < 1152 * 384; i += stride) {
    int op = i / 384, kk = i - op * 384;
    int t3 = op / 384, rem = op - t3 * 384;
    int h = rem >> 5, d = rem & 31;
    int o = h * 96 + d * 3 + t3;
    qkv_wp[i] = f2bf(qkv_w[o * 384 + kk]);
  }
  for (int i = tid0; i < 1152; i += stride) {
    int t3 = i / 384, rem = i - t3 * 384;
    int h = rem >> 5, d = rem & 31;
    qkv_bp[i] = qkv_b[h * 96 + d * 3 + t3];
  }
  for (int i = tid0; i < 384 * 384; i += stride) out_wb[i] = f2bf(out_w[i]);
  // zero vt padding rows j=49..63 : vt[((b*12+h)*32+d)*64 + j]
  int padcnt = Bwin * 12 * 32 * 15;
  for (int i = tid0; i < padcnt; i += stride) {
    int j = 49 + (i % 15);
    int rest = i / 15;
    vt[(size_t)rest * 64 + j] = 0;
  }
}

// ---------------- GEMM C = A @ B^T (+bias), 128x128 tile, BK=64 ----------------
// MODE 1: qkv epilogue (bf16 -> qk buffer [M][768] cols o'<768; v -> vt[(b*12+h)*32+d][64] transposed)
// MODE 2: f32 epilogue (+bias) -> outF [M][384]
template <int MODE>
__global__ __launch_bounds__(256) void gemm_bt(const u16* __restrict__ A, const u16* __restrict__ Bm,
                                               const float* __restrict__ bias,
                                               u16* __restrict__ outQK, u16* __restrict__ outVT,
                                               float* __restrict__ outF, int K, int ntiles) {
  __shared__ u16 As[128 * 64], Bs[128 * 64];
  int bid = blockIdx.x;
  int bm = bid / ntiles, bn = bid - bm * ntiles;
  size_t mBase = (size_t)bm * 128;
  int nBase = bn * 128;
  int t = threadIdx.x, lane = t & 63, wid = t >> 6;
  int wm = (wid >> 1) * 64, wn = (wid & 1) * 64;
  int lrow = lane & 15, kg = lane >> 4;
  int srow = t >> 3, soff = (t & 7) * 8;  // staging: 8 chunks/row of 16B
  f32x4 acc[4][4] = {};
  for (int ks = 0; ks < K; ks += 64) {
    __syncthreads();
#pragma unroll
    for (int i = 0; i < 4; i++) {
      int row = srow + 32 * i;
      cp16(A + (mBase + row) * K + ks + soff, As + (t + 256 * i) * 8);
    }
#pragma unroll
    for (int i = 0; i < 4; i++) {
      int row = srow + 32 * i;
      cp16(Bm + ((size_t)(nBase + row)) * K + ks + soff, Bs + (t + 256 * i) * 8);
    }
    __syncthreads();
#pragma unroll
    for (int kk = 0; kk < 2; kk++) {
      bf16x8 af[4], bfr[4];
#pragma unroll
      for (int mt = 0; mt < 4; mt++)
        af[mt] = *(const bf16x8*)(As + (wm + mt * 16 + lrow) * 64 + kk * 32 + kg * 8);
#pragma unroll
      for (int nt = 0; nt < 4; nt++)
        bfr[nt] = *(const bf16x8*)(Bs + (wn + nt * 16 + lrow) * 64 + kk * 32 + kg * 8);
#pragma unroll
      for (int mt = 0; mt < 4; mt++)
#pragma unroll
        for (int nt = 0; nt < 4; nt++)
          acc[mt][nt] = __builtin_amdgcn_mfma_f32_16x16x32_bf16(af[mt], bfr[nt], acc[mt][nt], 0, 0, 0);
    }
  }
#pragma unroll
  for (int mt = 0; mt < 4; mt++) {
#pragma unroll
    for (int nt = 0; nt < 4; nt++) {
      int col = nBase + wn + nt * 16 + lrow;
      float bv = bias[col];
      f32x4 a = acc[mt][nt];
      if (MODE == 1) {
        int t3 = col / 384, rem = col - t3 * 384;
        int hh = rem >> 5, dd = rem & 31;
#pragma unroll
        for (int r = 0; r < 4; r++) {
          int m = (int)mBase + wm + mt * 16 + kg * 4 + r;
          u16 v = f2bf(a[r] + bv);
          if (t3 < 2) {
            outQK[(size_t)m * 768 + col] = v;
          } else {
            int b = m / 49, n = m - b * 49;
            outVT[(((size_t)b * 12 + hh) * 32 + dd) * 64 + n] = v;
          }
        }
      } else {
#pragma unroll
        for (int r = 0; r < 4; r++) {
          int m = (int)mBase + wm + mt * 16 + kg * 4 + r;
          outF[(size_t)m * 384 + col] = a[r] + bv;
        }
      }
    }
  }
}

// ---------------- attention: 1 block per window, wave w -> heads w*3..w*3+2 ----------------
__global__ __launch_bounds__(256) void attn_kernel(const u16* __restrict__ qk, const u16* __restrict__ vt,
                                                   const int* __restrict__ rp_index,
                                                   const float* __restrict__ rp_table,
                                                   const float* __restrict__ mask,
                                                   u16* __restrict__ aout, int nW) {
  __shared__ float mask_s[2401];
  __shared__ int idx_s[2401];
  __shared__ float tab_s[169 * 12];
  __shared__ u16 p_lds[4 * 4096];
  int b = blockIdx.x, t = threadIdx.x, lane = t & 63, wid = t >> 6;
  const float* mrow = mask + (size_t)(b % nW) * 2401;
  for (int i = t; i < 2401; i += 256) {
    mask_s[i] = mrow[i];
    idx_s[i] = rp_index[i];
  }
  for (int i = t; i < 2028; i += 256) tab_s[i] = rp_table[i];
  __syncthreads();
  int lrow = lane & 15, kg = lane >> 4;
  u16* pw = p_lds + wid * 4096;
  const float scale = 0.17677669529663687f;  // 32^-0.5
  bf16x8 zer = {0, 0, 0, 0, 0, 0, 0, 0};
  for (int hi = 0; hi < 3; ++hi) {
    int h = wid * 3 + hi;
    bf16x8 qf[4], kf[4];
#pragma unroll
    for (int mt = 0; mt < 4; mt++) {
      int n = mt * 16 + lrow;
      const u16* qbase = qk + ((size_t)(b * 49 + n)) * 768 + h * 32 + kg * 8;
      qf[mt] = (n < 49) ? *(const bf16x8*)qbase : zer;
      kf[mt] = (n < 49) ? *(const bf16x8*)(qbase + 384) : zer;
    }
    f32x4 s[4][4];
#pragma unroll
    for (int mt = 0; mt < 4; mt++)
#pragma unroll
      for (int nt = 0; nt < 4; nt++) {
        f32x4 z = {0.f, 0.f, 0.f, 0.f};
        s[mt][nt] = __builtin_amdgcn_mfma_f32_16x16x32_bf16(qf[mt], kf[nt], z, 0, 0, 0);
      }
    // softmax rows: i = mt*16 + kg*4 + r ; cols: j = nt*16 + lrow
#pragma unroll
    for (int mt = 0; mt < 4; mt++) {
#pragma unroll
      for (int r = 0; r < 4; r++) {
        int i = mt * 16 + kg * 4 + r;
        float vals[4];
        float mx = -1e30f;
#pragma unroll
        for (int nt = 0; nt < 4; nt++) {
          int j = nt * 16 + lrow;
          float v;
          if (i < 49 && j < 49) {
            int ij = i * 49 + j;
            v = s[mt][nt][r] * scale + tab_s[idx_s[ij] * 12 + h] + mask_s[ij];
          } else {
            v = -1e30f;
          }
          vals[nt] = v;
          mx = fmaxf(mx, v);
        }
#pragma unroll
        for (int off = 1; off < 16; off <<= 1) mx = fmaxf(mx, __shfl_xor(mx, off, 64));
        float sum = 0.f;
#pragma unroll
        for (int nt = 0; nt < 4; nt++) {
          float p = __expf(vals[nt] - mx);
          vals[nt] = p;
          sum += p;
        }
#pragma unroll
        for (int off = 1; off < 16; off <<= 1) sum += __shfl_xor(sum, off, 64);
        float inv = 1.0f / sum;
#pragma unroll
        for (int nt = 0; nt < 4; nt++) {
          int j = nt * 16 + lrow;
          int addr = ((i * 64 + j) * 2) ^ ((i & 7) << 4);
          *(u16*)((char*)pw + addr) = f2bf(vals[nt] * inv);
        }
      }
    }
    asm volatile("s_waitcnt lgkmcnt(0)" ::: "memory");
    // PV: O[i][d] = sum_j P[i][j] * V[j][d] ; B-frag direct from vt (V transposed, padded j zeroed)
    f32x4 o[4][2];
#pragma unroll
    for (int mt = 0; mt < 4; mt++)
#pragma unroll
      for (int nt = 0; nt < 2; nt++) o[mt][nt] = (f32x4){0.f, 0.f, 0.f, 0.f};
#pragma unroll
    for (int kt = 0; kt < 2; kt++) {
      bf16x8 pf[4], vf[2];
#pragma unroll
      for (int mt = 0; mt < 4; mt++) {
        int i = mt * 16 + lrow;
        int j = kt * 32 + kg * 8;
        int addr = ((i * 64 + j) * 2) ^ ((i & 7) << 4);
        pf[mt] = *(const bf16x8*)((const char*)pw + addr);
      }
#pragma unroll
      for (int nt = 0; nt < 2; nt++) {
        int d = nt * 16 + lrow;
        vf[nt] = *(const bf16x8*)(vt + ((size_t)(b * 12 + h) * 32 + d) * 64 + kt * 32 + kg * 8);
      }
#pragma unroll
      for (int mt = 0; mt < 4; mt++)
#pragma unroll
        for (int nt = 0; nt < 2; nt++)
          o[mt][nt] = __builtin_amdgcn_mfma_f32_16x16x32_bf16(pf[mt], vf[nt], o[mt][nt], 0, 0, 0);
    }
#pragma unroll
    for (int mt = 0; mt < 4; mt++) {
#pragma unroll
      for (int nt = 0; nt < 2; nt++) {
#pragma unroll
        for (int r = 0; r < 4; r++) {
          int i = mt * 16 + kg * 4 + r;
          if (i < 49) {
            int d = nt * 16 + lrow;
            aout[((size_t)(b * 49 + i)) * 384 + h * 32 + d] = f2bf(o[mt][nt][r]);
          }
        }
      }
    }
  }
}

extern "C" void kernel_launch(void* const* d_in, const int* in_sizes, int n_in,
                              void* d_out, int out_size, void* d_ws, size_t ws_size,
                              hipStream_t stream) {
  const float* x = (const float*)d_in[0];
  const float* qkv_w = (const float*)d_in[1];
  const float* qkv_b = (const float*)d_in[2];
  const float* rp_table = (const float*)d_in[3];
  const float* out_w = (const float*)d_in[4];
  const float* out_b = (const float*)d_in[5];
  const int* rp_index = (const int*)d_in[6];
  const float* mask = (const float*)d_in[7];

  int Bwin = in_sizes[0] / (49 * 384);  // 4096
  int nW = in_sizes[7] / (49 * 49);     // 64
  int M = Bwin * 49;                    // 200704 (divisible by 128)

  char* ws = (char*)d_ws;
  u16* xb = (u16*)(ws);                      // 154,140,672 B (also reused as attn_out)
  u16* qkbuf = (u16*)(ws + 154140672);       // 308,281,344 B : [M][768] bf16
  u16* vtbuf = (u16*)(ws + 462422016);       // 201,326,592 B : [B*12*32][64] bf16
  u16* qkv_wp = (u16*)(ws + 663748608);      // 884,736 B
  float* qkv_bp = (float*)(ws + 664633344);  // 4,608 B
  u16* out_wb = (u16*)(ws + 664637952);      // 294,912 B
  u16* attn_out = xb;                        // alias: xb dead after gemm1

  int n4 = in_sizes[0] / 4;
  cast_x_kernel<<<4096, 256, 0, stream>>>((const float4*)x, (ushort4*)xb, n4);
  prep_kernel<<<4096, 256, 0, stream>>>(qkv_w, qkv_b, out_w, qkv_wp, qkv_bp, out_wb, vtbuf, Bwin);
  gemm_bt<1><<<(M / 128) * 9, 256, 0, stream>>>(xb, qkv_wp, qkv_bp, qkbuf, vtbuf, nullptr, 384, 9);
  attn_kernel<<<Bwin, 256, 0, stream>>>(qkbuf, vtbuf, rp_index, rp_table, mask, attn_out, nW);
  gemm_bt<2><<<(M / 128) * 3, 256, 0, stream>>>(attn_out, out_wb, out_b, nullptr, nullptr,
                                                (float*)d_out, 384, 3);
}

// Round 2
// 1316.639 us; speedup vs baseline: 1.0133x; 1.0133x over previous
//
#include <hip/hip_runtime.h>
#include <hip/hip_bf16.h>

typedef short bf16x8 __attribute__((ext_vector_type(8)));
typedef float f32x4 __attribute__((ext_vector_type(4)));
typedef unsigned short u16;
typedef unsigned int u32;

__device__ __forceinline__ u16 f2bf(float f) {
  unsigned u = __float_as_uint(f);
  u += 0x7FFFu + ((u >> 16) & 1u);
  return (u16)(u >> 16);
}

__device__ __forceinline__ void cp16(const u16* g, u16* l) {
  __builtin_amdgcn_global_load_lds((const __attribute__((address_space(1))) u32*)(const void*)g,
                                   (__attribute__((address_space(3))) u32*)(void*)l, 16, 0, 0);
}

// ---------------- prep: cast x to bf16 ----------------
__global__ void cast_x_kernel(const float4* __restrict__ x, ushort4* __restrict__ xb, int n4) {
  int stride = gridDim.x * blockDim.x;
  for (int i = blockIdx.x * blockDim.x + threadIdx.x; i < n4; i += stride) {
    float4 v = x[i];
    ushort4 o;
    o.x = f2bf(v.x); o.y = f2bf(v.y); o.z = f2bf(v.z); o.w = f2bf(v.w);
    xb[i] = o;
  }
}

// ---------------- prep: weights permute+cast, vt pad zero ----------------
// qkv_w rows: o = h*96 + d*3 + t  (reference reshape (h,dh,3))
// permuted rows: o' = t*384 + h*32 + d
__global__ void prep_kernel(const float* __restrict__ qkv_w, const float* __restrict__ qkv_b,
                            const float* __restrict__ out_w,
                            u16* __restrict__ qkv_wp, float* __restrict__ qkv_bp,
                            u16* __restrict__ out_wb, u16* __restrict__ vt, int Bwin) {
  int stride = gridDim.x * blockDim.x;
  int tid0 = blockIdx.x * blockDim.x + threadIdx.x;
  for (int i = tid0; i < 1152 * 384; i += stride) {
    int op = i / 384, kk = i - op * 384;
    int t3 = op / 384, rem = op - t3 * 384;
    int h = rem >> 5, d = rem & 31;
    int o = h * 96 + d * 3 + t3;
    qkv_wp[i] = f2bf(qkv_w[o * 384 + kk]);
  }
  for (int i = tid0; i < 1152; i += stride) {
    int t3 = i / 384, rem = i - t3 * 384;
    int h = rem >> 5, d = rem & 31;
    qkv_bp[i] = qkv_b[h * 96 + d * 3 + t3];
  }
  for (int i = tid0; i < 384 * 384; i += stride) out_wb[i] = f2bf(out_w[i]);
  // zero vt padding rows j=49..63 : vt[((b*12+h)*32+d)*64 + j]
  int padcnt = Bwin * 12 * 32 * 15;
  for (int i = tid0; i < padcnt; i += stride) {
    int j = 49 + (i % 15);
    int rest = i / 15;
    vt[(size_t)rest * 64 + j] = 0;
  }
}

// ---------------- GEMM C = A @ B^T (+bias), 128x128 tile, BK=64 ----------------
// T2 LDS XOR swizzle: data for (row, 16B-chunk c) lives at byte row*128 + (c ^ (row&7))*16.
// global_load_lds dest stays LINEAR; the source chunk is pre-swizzled (rule 21).
// 2-phase prefetch (T3 minimum): STAGE(t+1) issued before compute(t); one barrier/K-step.
// MODE 1: qkv epilogue (bf16 -> qk buffer [M][768]; v -> vt[(b*12+h)*32+d][64] transposed)
// MODE 2: f32 epilogue (+bias) -> outF [M][384]
template <int MODE>
__global__ __launch_bounds__(256) void gemm_bt(const u16* __restrict__ A, const u16* __restrict__ Bm,
                                               const float* __restrict__ bias,
                                               u16* __restrict__ outQK, u16* __restrict__ outVT,
                                               float* __restrict__ outF, int K, int ntiles) {
  __shared__ u16 As[2][128 * 64], Bs[2][128 * 64];
  int nwg = gridDim.x;
  int bid0 = blockIdx.x;
  // T1 bijective XCD swizzle (nwg divisible by 8 for our grids)
  int bid = ((nwg & 7) == 0) ? ((bid0 & 7) * (nwg >> 3) + (bid0 >> 3)) : bid0;
  int bm = bid / ntiles, bn = bid - bm * ntiles;
  size_t mBase = (size_t)bm * 128;
  int nBase = bn * 128;
  int t = threadIdx.x, lane = t & 63, wid = t >> 6;
  int wm = (wid >> 1) * 64, wn = (wid & 1) * 64;
  int lrow = lane & 15, kg = lane >> 4;
  int srow = t >> 3;                          // staging row within 32-row group
  int schunk8 = (((t & 7) ^ (srow & 7)) * 8); // pre-swizzled source chunk (u16 units)
  f32x4 acc[4][4] = {};

  const u16* Arow = A + mBase * K;
  const u16* Brow = Bm + (size_t)nBase * K;

#define STAGE(buf, ks)                                                            \
  {                                                                               \
    _Pragma("unroll") for (int i = 0; i < 4; i++) {                               \
      int row = srow + 32 * i;                                                    \
      cp16(Arow + (size_t)row * K + (ks) + schunk8, &As[buf][(t + 256 * i) * 8]); \
      cp16(Brow + (size_t)row * K + (ks) + schunk8, &Bs[buf][(t + 256 * i) * 8]); \
    }                                                                             \
  }

  STAGE(0, 0);
  __syncthreads();
  int nk = K / 64;
  int buf = 0;
  for (int tk = 0; tk < nk; ++tk) {
    if (tk + 1 < nk) STAGE(buf ^ 1, (tk + 1) * 64);
#pragma unroll
    for (int kk = 0; kk < 2; kk++) {
      bf16x8 af[4], bfr[4];
#pragma unroll
      for (int mt = 0; mt < 4; mt++) {
        int ck = ((kk << 2) | kg) ^ (lrow & 7);
        af[mt] = *(const bf16x8*)(&As[buf][(wm + mt * 16 + lrow) * 64 + ck * 8]);
      }
#pragma unroll
      for (int nt = 0; nt < 4; nt++) {
        int ck = ((kk << 2) | kg) ^ (lrow & 7);
        bfr[nt] = *(const bf16x8*)(&Bs[buf][(wn + nt * 16 + lrow) * 64 + ck * 8]);
      }
#pragma unroll
      for (int mt = 0; mt < 4; mt++)
#pragma unroll
        for (int nt = 0; nt < 4; nt++)
          acc[mt][nt] = __builtin_amdgcn_mfma_f32_16x16x32_bf16(af[mt], bfr[nt], acc[mt][nt], 0, 0, 0);
    }
    if (tk + 1 < nk) {
      __syncthreads();  // drains vmcnt (stage landed) + lgkmcnt (reads done) then barrier
      buf ^= 1;
    }
  }
#undef STAGE

#pragma unroll
  for (int mt = 0; mt < 4; mt++) {
#pragma unroll
    for (int nt = 0; nt < 4; nt++) {
      int col = nBase + wn + nt * 16 + lrow;
      float bv = bias[col];
      f32x4 a = acc[mt][nt];
      if (MODE == 1) {
        int t3 = col / 384, rem = col - t3 * 384;
        int hh = rem >> 5, dd = rem & 31;
#pragma unroll
        for (int r = 0; r < 4; r++) {
          int m = (int)mBase + wm + mt * 16 + kg * 4 + r;
          u16 v = f2bf(a[r] + bv);
          if (t3 < 2) {
            outQK[(size_t)m * 768 + col] = v;
          } else {
            int b = m / 49, n = m - b * 49;
            outVT[(((size_t)b * 12 + hh) * 32 + dd) * 64 + n] = v;
          }
        }
      } else {
#pragma unroll
        for (int r = 0; r < 4; r++) {
          int m = (int)mBase + wm + mt * 16 + kg * 4 + r;
          outF[(size_t)m * 384 + col] = a[r] + bv;
        }
      }
    }
  }
}

// ---------------- attention: 1 block per window, wave w -> heads w*3..w*3+2 ----------------
__global__ __launch_bounds__(256) void attn_kernel(const u16* __restrict__ qk, const u16* __restrict__ vt,
                                                   const int* __restrict__ rp_index,
                                                   const float* __restrict__ rp_table,
                                                   const float* __restrict__ mask,
                                                   u16* __restrict__ aout, int nW) {
  __shared__ float mask_s[2401];
  __shared__ int idx_s[2401];
  __shared__ float tab_s[169 * 12];
  __shared__ u16 p_lds[4 * 4096];
  int b = blockIdx.x, t = threadIdx.x, lane = t & 63, wid = t >> 6;
  const float* mrow = mask + (size_t)(b % nW) * 2401;
  for (int i = t; i < 2401; i += 256) {
    mask_s[i] = mrow[i];
    idx_s[i] = rp_index[i];
  }
  for (int i = t; i < 2028; i += 256) tab_s[i] = rp_table[i];
  __syncthreads();
  int lrow = lane & 15, kg = lane >> 4;
  u16* pw = p_lds + wid * 4096;
  const float scale = 0.17677669529663687f;  // 32^-0.5
  bf16x8 zer = {0, 0, 0, 0, 0, 0, 0, 0};
  for (int hi = 0; hi < 3; ++hi) {
    int h = wid * 3 + hi;
    bf16x8 qf[4], kf[4];
#pragma unroll
    for (int mt = 0; mt < 4; mt++) {
      int n = mt * 16 + lrow;
      const u16* qbase = qk + ((size_t)(b * 49 + n)) * 768 + h * 32 + kg * 8;
      qf[mt] = (n < 49) ? *(const bf16x8*)qbase : zer;
      kf[mt] = (n < 49) ? *(const bf16x8*)(qbase + 384) : zer;
    }
    f32x4 s[4][4];
#pragma unroll
    for (int mt = 0; mt < 4; mt++)
#pragma unroll
      for (int nt = 0; nt < 4; nt++) {
        f32x4 z = {0.f, 0.f, 0.f, 0.f};
        s[mt][nt] = __builtin_amdgcn_mfma_f32_16x16x32_bf16(qf[mt], kf[nt], z, 0, 0, 0);
      }
    // softmax rows: i = mt*16 + kg*4 + r ; cols: j = nt*16 + lrow
#pragma unroll
    for (int mt = 0; mt < 4; mt++) {
#pragma unroll
      for (int r = 0; r < 4; r++) {
        int i = mt * 16 + kg * 4 + r;
        float vals[4];
        float mx = -1e30f;
#pragma unroll
        for (int nt = 0; nt < 4; nt++) {
          int j = nt * 16 + lrow;
          float v;
          if (i < 49 && j < 49) {
            int ij = i * 49 + j;
            v = s[mt][nt][r] * scale + tab_s[idx_s[ij] * 12 + h] + mask_s[ij];
          } else {
            v = -1e30f;
          }
          vals[nt] = v;
          mx = fmaxf(mx, v);
        }
#pragma unroll
        for (int off = 1; off < 16; off <<= 1) mx = fmaxf(mx, __shfl_xor(mx, off, 64));
        float sum = 0.f;
#pragma unroll
        for (int nt = 0; nt < 4; nt++) {
          float p = __expf(vals[nt] - mx);
          vals[nt] = p;
          sum += p;
        }
#pragma unroll
        for (int off = 1; off < 16; off <<= 1) sum += __shfl_xor(sum, off, 64);
        float inv = 1.0f / sum;
#pragma unroll
        for (int nt = 0; nt < 4; nt++) {
          int j = nt * 16 + lrow;
          int addr = ((i * 64 + j) * 2) ^ ((i & 7) << 4);
          *(u16*)((char*)pw + addr) = f2bf(vals[nt] * inv);
        }
      }
    }
    asm volatile("s_waitcnt lgkmcnt(0)" ::: "memory");
    // PV: O[i][d] = sum_j P[i][j] * V[j][d] ; B-frag direct from vt (V transposed, padded j zeroed)
    f32x4 o[4][2];
#pragma unroll
    for (int mt = 0; mt < 4; mt++)
#pragma unroll
      for (int nt = 0; nt < 2; nt++) o[mt][nt] = (f32x4){0.f, 0.f, 0.f, 0.f};
#pragma unroll
    for (int kt = 0; kt < 2; kt++) {
      bf16x8 pf[4], vf[2];
#pragma unroll
      for (int mt = 0; mt < 4; mt++) {
        int i = mt * 16 + lrow;
        int j = kt * 32 + kg * 8;
        int addr = ((i * 64 + j) * 2) ^ ((i & 7) << 4);
        pf[mt] = *(const bf16x8*)((const char*)pw + addr);
      }
#pragma unroll
      for (int nt = 0; nt < 2; nt++) {
        int d = nt * 16 + lrow;
        vf[nt] = *(const bf16x8*)(vt + ((size_t)(b * 12 + h) * 32 + d) * 64 + kt * 32 + kg * 8);
      }
#pragma unroll
      for (int mt = 0; mt < 4; mt++)
#pragma unroll
        for (int nt = 0; nt < 2; nt++)
          o[mt][nt] = __builtin_amdgcn_mfma_f32_16x16x32_bf16(pf[mt], vf[nt], o[mt][nt], 0, 0, 0);
    }
#pragma unroll
    for (int mt = 0; mt < 4; mt++) {
#pragma unroll
      for (int nt = 0; nt < 2; nt++) {
#pragma unroll
        for (int r = 0; r < 4; r++) {
          int i = mt * 16 + kg * 4 + r;
          if (i < 49) {
            int d = nt * 16 + lrow;
            aout[((size_t)(b * 49 + i)) * 384 + h * 32 + d] = f2bf(o[mt][nt][r]);
          }
        }
      }
    }
  }
}

extern "C" void kernel_launch(void* const* d_in, const int* in_sizes, int n_in,
                              void* d_out, int out_size, void* d_ws, size_t ws_size,
                              hipStream_t stream) {
  const float* x = (const float*)d_in[0];
  const float* qkv_w = (const float*)d_in[1];
  const float* qkv_b = (const float*)d_in[2];
  const float* rp_table = (const float*)d_in[3];
  const float* out_w = (const float*)d_in[4];
  const float* out_b = (const float*)d_in[5];
  const int* rp_index = (const int*)d_in[6];
  const float* mask = (const float*)d_in[7];

  int Bwin = in_sizes[0] / (49 * 384);  // 4096
  int nW = in_sizes[7] / (49 * 49);     // 64
  int M = Bwin * 49;                    // 200704 (divisible by 128)

  char* ws = (char*)d_ws;
  u16* xb = (u16*)(ws);                      // 154,140,672 B (also reused as attn_out)
  u16* qkbuf = (u16*)(ws + 154140672);       // 308,281,344 B : [M][768] bf16
  u16* vtbuf = (u16*)(ws + 462422016);       // 201,326,592 B : [B*12*32][64] bf16
  u16* qkv_wp = (u16*)(ws + 663748608);      // 884,736 B
  float* qkv_bp = (float*)(ws + 664633344);  // 4,608 B
  u16* out_wb = (u16*)(ws + 664637952);      // 294,912 B
  u16* attn_out = xb;                        // alias: xb dead after gemm1

  int n4 = in_sizes[0] / 4;
  cast_x_kernel<<<4096, 256, 0, stream>>>((const float4*)x, (ushort4*)xb, n4);
  prep_kernel<<<4096, 256, 0, stream>>>(qkv_w, qkv_b, out_w, qkv_wp, qkv_bp, out_wb, vtbuf, Bwin);
  gemm_bt<1><<<(M / 128) * 9, 256, 0, stream>>>(xb, qkv_wp, qkv_bp, qkbuf, vtbuf, nullptr, 384, 9);
  attn_kernel<<<Bwin, 256, 0, stream>>>(qkbuf, vtbuf, rp_index, rp_table, mask, attn_out, nW);
  gemm_bt<2><<<(M / 128) * 3, 256, 0, stream>>>(attn_out, out_wb, out_b, nullptr, nullptr,
                                                (float*)d_out, 384, 3);
}

// Round 3
// 1179.544 us; speedup vs baseline: 1.1311x; 1.1162x over previous
//
#include <hip/hip_runtime.h>
#include <hip/hip_bf16.h>

typedef short bf16x8 __attribute__((ext_vector_type(8)));
typedef float f32x4 __attribute__((ext_vector_type(4)));
typedef unsigned short u16;
typedef unsigned int u32;

__device__ __forceinline__ u16 f2bf(float f) {
  unsigned u = __float_as_uint(f);
  u += 0x7FFFu + ((u >> 16) & 1u);
  return (u16)(u >> 16);
}

__device__ __forceinline__ void cp16(const u16* g, u16* l) {
  __builtin_amdgcn_global_load_lds((const __attribute__((address_space(1))) u32*)(const void*)g,
                                   (__attribute__((address_space(3))) u32*)(void*)l, 16, 0, 0);
}

// ---------------- prep: cast x to bf16 ----------------
__global__ void cast_x_kernel(const float4* __restrict__ x, ushort4* __restrict__ xb, int n4) {
  int stride = gridDim.x * blockDim.x;
  for (int i = blockIdx.x * blockDim.x + threadIdx.x; i < n4; i += stride) {
    float4 v = x[i];
    ushort4 o;
    o.x = f2bf(v.x); o.y = f2bf(v.y); o.z = f2bf(v.z); o.w = f2bf(v.w);
    xb[i] = o;
  }
}

// ---------------- prep: weights permute+cast ----------------
// qkv_w rows: o = h*96 + d*3 + t  (reference reshape (h,dh,3))
// permuted rows: o' = t*384 + h*32 + d
__global__ void prep_kernel(const float* __restrict__ qkv_w, const float* __restrict__ qkv_b,
                            const float* __restrict__ out_w,
                            u16* __restrict__ qkv_wp, float* __restrict__ qkv_bp,
                            u16* __restrict__ out_wb) {
  int stride = gridDim.x * blockDim.x;
  int tid0 = blockIdx.x * blockDim.x + threadIdx.x;
  for (int i = tid0; i < 1152 * 384; i += stride) {
    int op = i / 384, kk = i - op * 384;
    int t3 = op / 384, rem = op - t3 * 384;
    int h = rem >> 5, d = rem & 31;
    int o = h * 96 + d * 3 + t3;
    qkv_wp[i] = f2bf(qkv_w[o * 384 + kk]);
  }
  for (int i = tid0; i < 1152; i += stride) {
    int t3 = i / 384, rem = i - t3 * 384;
    int h = rem >> 5, d = rem & 31;
    qkv_bp[i] = qkv_b[h * 96 + d * 3 + t3];
  }
  for (int i = tid0; i < 384 * 384; i += stride) out_wb[i] = f2bf(out_w[i]);
}

// ---------------- GEMM C = A @ B^T (+bias), 128x128 tile, BK=64 ----------------
// Single-buffer 32 KB LDS -> 5 blocks/CU; rely on inter-block overlap (m114) to hide
// each block's stage->drain latency. T2 XOR swizzle (linear gload_lds dest, pre-swizzled
// global source chunk, XOR'd ds_read) + T1 bijective XCD swizzle.
// MODE 1: qkv epilogue (bf16 -> qk buffer [M][768]; v -> vt[(b*12+h)*32+d][64] transposed)
// MODE 2: f32 epilogue (+bias) -> outF [M][384]
template <int MODE>
__global__ __launch_bounds__(256) void gemm_bt(const u16* __restrict__ A, const u16* __restrict__ Bm,
                                               const float* __restrict__ bias,
                                               u16* __restrict__ outQK, u16* __restrict__ outVT,
                                               float* __restrict__ outF, int K, int ntiles) {
  __shared__ u16 As[128 * 64], Bs[128 * 64];
  int nwg = gridDim.x;
  int bid0 = blockIdx.x;
  // T1 bijective XCD swizzle (nwg divisible by 8 for our grids)
  int bid = ((nwg & 7) == 0) ? ((bid0 & 7) * (nwg >> 3) + (bid0 >> 3)) : bid0;
  int bm = bid / ntiles, bn = bid - bm * ntiles;
  size_t mBase = (size_t)bm * 128;
  int nBase = bn * 128;
  int t = threadIdx.x, lane = t & 63, wid = t >> 6;
  int wm = (wid >> 1) * 64, wn = (wid & 1) * 64;
  int lrow = lane & 15, kg = lane >> 4;
  int srow = t >> 3;                           // staging row within 32-row group
  int schunk8 = (((t & 7) ^ (srow & 7)) * 8);  // pre-swizzled source chunk (u16 units)
  f32x4 acc[4][4] = {};

  const u16* Arow = A + mBase * K;
  const u16* Brow = Bm + (size_t)nBase * K;

  int nk = K / 64;
  for (int tk = 0; tk < nk; ++tk) {
    __syncthreads();  // previous iteration's LDS reads complete before overwrite
#pragma unroll
    for (int i = 0; i < 4; i++) {
      int row = srow + 32 * i;
      cp16(Arow + (size_t)row * K + tk * 64 + schunk8, &As[(t + 256 * i) * 8]);
      cp16(Brow + (size_t)row * K + tk * 64 + schunk8, &Bs[(t + 256 * i) * 8]);
    }
    __syncthreads();  // stage landed (vmcnt drained by barrier semantics)
#pragma unroll
    for (int kk = 0; kk < 2; kk++) {
      bf16x8 af[4], bfr[4];
      int ck = ((kk << 2) | kg) ^ (lrow & 7);
#pragma unroll
      for (int mt = 0; mt < 4; mt++)
        af[mt] = *(const bf16x8*)(&As[(wm + mt * 16 + lrow) * 64 + ck * 8]);
#pragma unroll
      for (int nt = 0; nt < 4; nt++)
        bfr[nt] = *(const bf16x8*)(&Bs[(wn + nt * 16 + lrow) * 64 + ck * 8]);
#pragma unroll
      for (int mt = 0; mt < 4; mt++)
#pragma unroll
        for (int nt = 0; nt < 4; nt++)
          acc[mt][nt] = __builtin_amdgcn_mfma_f32_16x16x32_bf16(af[mt], bfr[nt], acc[mt][nt], 0, 0, 0);
    }
  }

  if (MODE == 1) {
    int t3 = nBase / 384;  // block-uniform: 384/128==3 so no split within a tile
    int remBase = nBase - t3 * 384;
#pragma unroll
    for (int mt = 0; mt < 4; mt++) {
#pragma unroll
      for (int r = 0; r < 4; r++) {
        int m = (int)mBase + wm + mt * 16 + kg * 4 + r;
        int b = m / 49, n = m - b * 49;
#pragma unroll
        for (int nt = 0; nt < 4; nt++) {
          int col = nBase + wn + nt * 16 + lrow;
          u16 v = f2bf(acc[mt][nt][r] + bias[col]);
          if (t3 < 2) {
            outQK[(size_t)m * 768 + col] = v;
          } else {
            int rem = remBase + wn + nt * 16 + lrow;
            int hh = rem >> 5, dd = rem & 31;
            outVT[(((size_t)b * 12 + hh) * 32 + dd) * 64 + n] = v;
          }
        }
      }
    }
  } else {
#pragma unroll
    for (int mt = 0; mt < 4; mt++) {
#pragma unroll
      for (int nt = 0; nt < 4; nt++) {
        int col = nBase + wn + nt * 16 + lrow;
        float bv = bias[col];
#pragma unroll
        for (int r = 0; r < 4; r++) {
          int m = (int)mBase + wm + mt * 16 + kg * 4 + r;
          outF[(size_t)m * 384 + col] = acc[mt][nt][r] + bv;
        }
      }
    }
  }
}

// ---------------- attention: 1 block per window, wave w -> heads w*3..w*3+2 ----------------
__global__ __launch_bounds__(256) void attn_kernel(const u16* __restrict__ qk, const u16* __restrict__ vt,
                                                   const int* __restrict__ rp_index,
                                                   const float* __restrict__ rp_table,
                                                   const float* __restrict__ mask,
                                                   u16* __restrict__ aout, int nW) {
  __shared__ float mask_s[2401];
  __shared__ int idx_s[2401];
  __shared__ float tab_s[169 * 12];
  __shared__ u16 p_lds[4 * 4096];
  int b = blockIdx.x, t = threadIdx.x, lane = t & 63, wid = t >> 6;
  const float* mrow = mask + (size_t)(b % nW) * 2401;
  for (int i = t; i < 2401; i += 256) {
    mask_s[i] = mrow[i];
    idx_s[i] = rp_index[i];
  }
  for (int i = t; i < 2028; i += 256) tab_s[i] = rp_table[i];
  __syncthreads();
  int lrow = lane & 15, kg = lane >> 4;
  u16* pw = p_lds + wid * 4096;
  const float scale = 0.17677669529663687f;  // 32^-0.5
  bf16x8 zer = {0, 0, 0, 0, 0, 0, 0, 0};
  for (int hi = 0; hi < 3; ++hi) {
    int h = wid * 3 + hi;
    bf16x8 qf[4], kf[4];
#pragma unroll
    for (int mt = 0; mt < 4; mt++) {
      int n = mt * 16 + lrow;
      const u16* qbase = qk + ((size_t)(b * 49 + n)) * 768 + h * 32 + kg * 8;
      qf[mt] = (n < 49) ? *(const bf16x8*)qbase : zer;
      kf[mt] = (n < 49) ? *(const bf16x8*)(qbase + 384) : zer;
    }
    f32x4 s[4][4];
#pragma unroll
    for (int mt = 0; mt < 4; mt++)
#pragma unroll
      for (int nt = 0; nt < 4; nt++) {
        f32x4 z = {0.f, 0.f, 0.f, 0.f};
        s[mt][nt] = __builtin_amdgcn_mfma_f32_16x16x32_bf16(qf[mt], kf[nt], z, 0, 0, 0);
      }
    // softmax rows: i = mt*16 + kg*4 + r ; cols: j = nt*16 + lrow
#pragma unroll
    for (int mt = 0; mt < 4; mt++) {
#pragma unroll
      for (int r = 0; r < 4; r++) {
        int i = mt * 16 + kg * 4 + r;
        float vals[4];
        float mx = -1e30f;
#pragma unroll
        for (int nt = 0; nt < 4; nt++) {
          int j = nt * 16 + lrow;
          float v;
          if (i < 49 && j < 49) {
            int ij = i * 49 + j;
            v = s[mt][nt][r] * scale + tab_s[idx_s[ij] * 12 + h] + mask_s[ij];
          } else {
            v = -1e30f;
          }
          vals[nt] = v;
          mx = fmaxf(mx, v);
        }
#pragma unroll
        for (int off = 1; off < 16; off <<= 1) mx = fmaxf(mx, __shfl_xor(mx, off, 64));
        float sum = 0.f;
#pragma unroll
        for (int nt = 0; nt < 4; nt++) {
          float p = __expf(vals[nt] - mx);
          vals[nt] = p;
          sum += p;
        }
#pragma unroll
        for (int off = 1; off < 16; off <<= 1) sum += __shfl_xor(sum, off, 64);
        float inv = 1.0f / sum;
#pragma unroll
        for (int nt = 0; nt < 4; nt++) {
          int j = nt * 16 + lrow;
          int addr = ((i * 64 + j) * 2) ^ ((i & 7) << 4);
          *(u16*)((char*)pw + addr) = f2bf(vals[nt] * inv);
        }
      }
    }
    asm volatile("s_waitcnt lgkmcnt(0)" ::: "memory");
    // PV: O[i][d] = sum_j P[i][j] * V[j][d] ; B-frag direct from vt (V transposed).
    // vt pad rows j=49..63 are never initialized -> mask them to 0 in-register
    // (P[:,j>=49]==0 already, but 0*NaN protection requires the mask).
    f32x4 o[4][2];
#pragma unroll
    for (int mt = 0; mt < 4; mt++)
#pragma unroll
      for (int nt = 0; nt < 2; nt++) o[mt][nt] = (f32x4){0.f, 0.f, 0.f, 0.f};
#pragma unroll
    for (int kt = 0; kt < 2; kt++) {
      bf16x8 pf[4], vf[2];
#pragma unroll
      for (int mt = 0; mt < 4; mt++) {
        int i = mt * 16 + lrow;
        int j = kt * 32 + kg * 8;
        int addr = ((i * 64 + j) * 2) ^ ((i & 7) << 4);
        pf[mt] = *(const bf16x8*)((const char*)pw + addr);
      }
#pragma unroll
      for (int nt = 0; nt < 2; nt++) {
        int d = nt * 16 + lrow;
        vf[nt] = *(const bf16x8*)(vt + ((size_t)(b * 12 + h) * 32 + d) * 64 + kt * 32 + kg * 8);
        if (kt == 1) {
          int j0 = 32 + kg * 8;
#pragma unroll
          for (int e = 0; e < 8; e++)
            if (j0 + e >= 49) vf[nt][e] = 0;
        }
      }
#pragma unroll
      for (int mt = 0; mt < 4; mt++)
#pragma unroll
        for (int nt = 0; nt < 2; nt++)
          o[mt][nt] = __builtin_amdgcn_mfma_f32_16x16x32_bf16(pf[mt], vf[nt], o[mt][nt], 0, 0, 0);
    }
#pragma unroll
    for (int mt = 0; mt < 4; mt++) {
#pragma unroll
      for (int nt = 0; nt < 2; nt++) {
#pragma unroll
        for (int r = 0; r < 4; r++) {
          int i = mt * 16 + kg * 4 + r;
          if (i < 49) {
            int d = nt * 16 + lrow;
            aout[((size_t)(b * 49 + i)) * 384 + h * 32 + d] = f2bf(o[mt][nt][r]);
          }
        }
      }
    }
  }
}

extern "C" void kernel_launch(void* const* d_in, const int* in_sizes, int n_in,
                              void* d_out, int out_size, void* d_ws, size_t ws_size,
                              hipStream_t stream) {
  const float* x = (const float*)d_in[0];
  const float* qkv_w = (const float*)d_in[1];
  const float* qkv_b = (const float*)d_in[2];
  const float* rp_table = (const float*)d_in[3];
  const float* out_w = (const float*)d_in[4];
  const float* out_b = (const float*)d_in[5];
  const int* rp_index = (const int*)d_in[6];
  const float* mask = (const float*)d_in[7];

  int Bwin = in_sizes[0] / (49 * 384);  // 4096
  int nW = in_sizes[7] / (49 * 49);     // 64
  int M = Bwin * 49;                    // 200704 (divisible by 128)

  char* ws = (char*)d_ws;
  u16* xb = (u16*)(ws);                      // 154,140,672 B (also reused as attn_out)
  u16* qkbuf = (u16*)(ws + 154140672);       // 308,281,344 B : [M][768] bf16
  u16* vtbuf = (u16*)(ws + 462422016);       // 201,326,592 B : [B*12*32][64] bf16
  u16* qkv_wp = (u16*)(ws + 663748608);      // 884,736 B
  float* qkv_bp = (float*)(ws + 664633344);  // 4,608 B
  u16* out_wb = (u16*)(ws + 664637952);      // 294,912 B
  u16* attn_out = xb;                        // alias: xb dead after gemm1

  int n4 = in_sizes[0] / 4;
  cast_x_kernel<<<4096, 256, 0, stream>>>((const float4*)x, (ushort4*)xb, n4);
  prep_kernel<<<1184, 256, 0, stream>>>(qkv_w, qkv_b, out_w, qkv_wp, qkv_bp, out_wb);
  gemm_bt<1><<<(M / 128) * 9, 256, 0, stream>>>(xb, qkv_wp, qkv_bp, qkbuf, vtbuf, nullptr, 384, 9);
  attn_kernel<<<Bwin, 256, 0, stream>>>(qkbuf, vtbuf, rp_index, rp_table, mask, attn_out, nW);
  gemm_bt<2><<<(M / 128) * 3, 256, 0, stream>>>(attn_out, out_wb, out_b, nullptr, nullptr,
                                                (float*)d_out, 384, 3);
}

// Round 4
// 1171.451 us; speedup vs baseline: 1.1389x; 1.0069x over previous
//
#include <hip/hip_runtime.h>
#include <hip/hip_bf16.h>

typedef short bf16x8 __attribute__((ext_vector_type(8)));
typedef float f32x4 __attribute__((ext_vector_type(4)));
typedef unsigned short u16;
typedef unsigned int u32;

__device__ __forceinline__ u16 f2bf(float f) {
  unsigned u = __float_as_uint(f);
  u += 0x7FFFu + ((u >> 16) & 1u);
  return (u16)(u >> 16);
}

__device__ __forceinline__ void cp16(const u16* g, u16* l) {
  __builtin_amdgcn_global_load_lds((const __attribute__((address_space(1))) u32*)(const void*)g,
                                   (__attribute__((address_space(3))) u32*)(void*)l, 16, 0, 0);
}

// ---------------- prep: cast x to bf16 ----------------
__global__ void cast_x_kernel(const float4* __restrict__ x, ushort4* __restrict__ xb, int n4) {
  int stride = gridDim.x * blockDim.x;
  for (int i = blockIdx.x * blockDim.x + threadIdx.x; i < n4; i += stride) {
    float4 v = x[i];
    ushort4 o;
    o.x = f2bf(v.x); o.y = f2bf(v.y); o.z = f2bf(v.z); o.w = f2bf(v.w);
    xb[i] = o;
  }
}

// ---------------- prep: weights permute+cast ----------------
// qkv_w rows: o = h*96 + d*3 + t  (reference reshape (h,dh,3))
// permuted rows: o' = t*384 + h*32 + d
__global__ void prep_kernel(const float* __restrict__ qkv_w, const float* __restrict__ qkv_b,
                            const float* __restrict__ out_w,
                            u16* __restrict__ qkv_wp, float* __restrict__ qkv_bp,
                            u16* __restrict__ out_wb) {
  int stride = gridDim.x * blockDim.x;
  int tid0 = blockIdx.x * blockDim.x + threadIdx.x;
  for (int i = tid0; i < 1152 * 384; i += stride) {
    int op = i / 384, kk = i - op * 384;
    int t3 = op / 384, rem = op - t3 * 384;
    int h = rem >> 5, d = rem & 31;
    int o = h * 96 + d * 3 + t3;
    qkv_wp[i] = f2bf(qkv_w[o * 384 + kk]);
  }
  for (int i = tid0; i < 1152; i += stride) {
    int t3 = i / 384, rem = i - t3 * 384;
    int h = rem >> 5, d = rem & 31;
    qkv_bp[i] = qkv_b[h * 96 + d * 3 + t3];
  }
  for (int i = tid0; i < 384 * 384; i += stride) out_wb[i] = f2bf(out_w[i]);
}

// ---------------- precompute combined bias+mask: bm[w][h][49][64] f32 ----------------
// j in [49,64) = -1e30 (kills padded K columns in softmax, branch-free)
__global__ void bmask_kernel(const int* __restrict__ rp_index, const float* __restrict__ rp_table,
                             const float* __restrict__ mask, float* __restrict__ bm, int nW) {
  int id = blockIdx.x * blockDim.x + threadIdx.x;
  int total = nW * 12 * 49 * 64;
  if (id >= total) return;
  int j = id & 63;
  int rest = id >> 6;  // [w][h][i]
  int i = rest % 49;
  rest /= 49;
  int h = rest % 12;
  int w = rest / 12;
  float v;
  if (j < 49) {
    int ij = i * 49 + j;
    v = rp_table[rp_index[ij] * 12 + h] + mask[(size_t)w * 2401 + ij];
  } else {
    v = -1e30f;
  }
  bm[id] = v;
}

// ---------------- GEMM C = A @ B^T (+bias), 128x128 tile, BK=64 ----------------
// Single-buffer 32 KB LDS; T2 XOR swizzle (linear gload_lds dest, pre-swizzled global
// source chunk, XOR'd ds_read) + T1 bijective XCD swizzle.
// MODE 1: qkv epilogue (bf16 -> qk buffer [M][768]; v -> vt[(b*12+h)*32+d][64] transposed)
// MODE 2: f32 epilogue (+bias) -> outF [M][384]
template <int MODE>
__global__ __launch_bounds__(256) void gemm_bt(const u16* __restrict__ A, const u16* __restrict__ Bm,
                                               const float* __restrict__ bias,
                                               u16* __restrict__ outQK, u16* __restrict__ outVT,
                                               float* __restrict__ outF, int K, int ntiles) {
  __shared__ u16 As[128 * 64], Bs[128 * 64];
  int nwg = gridDim.x;
  int bid0 = blockIdx.x;
  int bid = ((nwg & 7) == 0) ? ((bid0 & 7) * (nwg >> 3) + (bid0 >> 3)) : bid0;
  int bm = bid / ntiles, bn = bid - bm * ntiles;
  size_t mBase = (size_t)bm * 128;
  int nBase = bn * 128;
  int t = threadIdx.x, lane = t & 63, wid = t >> 6;
  int wm = (wid >> 1) * 64, wn = (wid & 1) * 64;
  int lrow = lane & 15, kg = lane >> 4;
  int srow = t >> 3;                           // staging row within 32-row group
  int schunk8 = (((t & 7) ^ (srow & 7)) * 8);  // pre-swizzled source chunk (u16 units)
  f32x4 acc[4][4] = {};

  const u16* Arow = A + mBase * K;
  const u16* Brow = Bm + (size_t)nBase * K;

  int nk = K / 64;
  for (int tk = 0; tk < nk; ++tk) {
    __syncthreads();  // previous iteration's LDS reads complete before overwrite
#pragma unroll
    for (int i = 0; i < 4; i++) {
      int row = srow + 32 * i;
      cp16(Arow + (size_t)row * K + tk * 64 + schunk8, &As[(t + 256 * i) * 8]);
      cp16(Brow + (size_t)row * K + tk * 64 + schunk8, &Bs[(t + 256 * i) * 8]);
    }
    __syncthreads();  // stage landed (vmcnt drained by barrier semantics)
#pragma unroll
    for (int kk = 0; kk < 2; kk++) {
      bf16x8 af[4], bfr[4];
      int ck = ((kk << 2) | kg) ^ (lrow & 7);
#pragma unroll
      for (int mt = 0; mt < 4; mt++)
        af[mt] = *(const bf16x8*)(&As[(wm + mt * 16 + lrow) * 64 + ck * 8]);
#pragma unroll
      for (int nt = 0; nt < 4; nt++)
        bfr[nt] = *(const bf16x8*)(&Bs[(wn + nt * 16 + lrow) * 64 + ck * 8]);
#pragma unroll
      for (int mt = 0; mt < 4; mt++)
#pragma unroll
        for (int nt = 0; nt < 4; nt++)
          acc[mt][nt] = __builtin_amdgcn_mfma_f32_16x16x32_bf16(af[mt], bfr[nt], acc[mt][nt], 0, 0, 0);
    }
  }

  if (MODE == 1) {
    int t3 = nBase / 384;  // block-uniform: 384/128==3 so no split within a tile
    int remBase = nBase - t3 * 384;
#pragma unroll
    for (int mt = 0; mt < 4; mt++) {
#pragma unroll
      for (int r = 0; r < 4; r++) {
        int m = (int)mBase + wm + mt * 16 + kg * 4 + r;
        int b = m / 49, n = m - b * 49;
#pragma unroll
        for (int nt = 0; nt < 4; nt++) {
          int col = nBase + wn + nt * 16 + lrow;
          u16 v = f2bf(acc[mt][nt][r] + bias[col]);
          if (t3 < 2) {
            outQK[(size_t)m * 768 + col] = v;
          } else {
            int rem = remBase + wn + nt * 16 + lrow;
            int hh = rem >> 5, dd = rem & 31;
            outVT[(((size_t)b * 12 + hh) * 32 + dd) * 64 + n] = v;
          }
        }
      }
    }
  } else {
#pragma unroll
    for (int mt = 0; mt < 4; mt++) {
#pragma unroll
      for (int nt = 0; nt < 4; nt++) {
        int col = nBase + wn + nt * 16 + lrow;
        float bv = bias[col];
#pragma unroll
        for (int r = 0; r < 4; r++) {
          int m = (int)mBase + wm + mt * 16 + kg * 4 + r;
          outF[(size_t)m * 384 + col] = acc[mt][nt][r] + bv;
        }
      }
    }
  }
}

// ---------------- attention: 1 block per window, wave w -> heads w*3..w*3+2 ----------------
// No LDS staging of bias/mask (precomputed bm, L3-resident); LDS = per-wave P buffer only
// (32 KB) -> no block barriers; __launch_bounds__(256,4) -> 4 blocks/CU target.
__global__ __launch_bounds__(256, 4) void attn_kernel(const u16* __restrict__ qk,
                                                      const u16* __restrict__ vt,
                                                      const float* __restrict__ bm,
                                                      u16* __restrict__ aout, int nW) {
  __shared__ u16 p_lds[4 * 4096];
  int b = blockIdx.x, t = threadIdx.x, lane = t & 63, wid = t >> 6;
  int lrow = lane & 15, kg = lane >> 4;
  u16* pw = p_lds + wid * 4096;
  const float scale = 0.17677669529663687f;  // 32^-0.5
  int w = b % nW;
  bf16x8 zer = {0, 0, 0, 0, 0, 0, 0, 0};
  for (int hi = 0; hi < 3; ++hi) {
    int h = wid * 3 + hi;
    const float* bmh = bm + ((size_t)w * 12 + h) * (49 * 64);
    bf16x8 qf[4], kf[4];
#pragma unroll
    for (int mt = 0; mt < 4; mt++) {
      int n = mt * 16 + lrow;
      const u16* qbase = qk + ((size_t)(b * 49 + n)) * 768 + h * 32 + kg * 8;
      qf[mt] = (n < 49) ? *(const bf16x8*)qbase : zer;
      kf[mt] = (n < 49) ? *(const bf16x8*)(qbase + 384) : zer;
    }
    f32x4 s[4][4];
#pragma unroll
    for (int mt = 0; mt < 4; mt++)
#pragma unroll
      for (int nt = 0; nt < 4; nt++) {
        f32x4 z = {0.f, 0.f, 0.f, 0.f};
        s[mt][nt] = __builtin_amdgcn_mfma_f32_16x16x32_bf16(qf[mt], kf[nt], z, 0, 0, 0);
      }
    // softmax rows: i = mt*16 + kg*4 + r ; cols: j = nt*16 + lrow
#pragma unroll
    for (int mt = 0; mt < 4; mt++) {
#pragma unroll
      for (int r = 0; r < 4; r++) {
        int i = mt * 16 + kg * 4 + r;
        int irow = (i < 49) ? i : 48;  // clamp: rows i>=49 are discarded, any finite bm works
        const float* bp = bmh + irow * 64 + lrow;
        float bmv[4];
#pragma unroll
        for (int nt = 0; nt < 4; nt++) bmv[nt] = bp[nt * 16];
        float vals[4];
        float mx = -1e30f;
#pragma unroll
        for (int nt = 0; nt < 4; nt++) {
          float v = fmaf(s[mt][nt][r], scale, bmv[nt]);
          vals[nt] = v;
          mx = fmaxf(mx, v);
        }
#pragma unroll
        for (int off = 1; off < 16; off <<= 1) mx = fmaxf(mx, __shfl_xor(mx, off, 64));
        float sum = 0.f;
#pragma unroll
        for (int nt = 0; nt < 4; nt++) {
          float p = __expf(vals[nt] - mx);
          vals[nt] = p;
          sum += p;
        }
#pragma unroll
        for (int off = 1; off < 16; off <<= 1) sum += __shfl_xor(sum, off, 64);
        float inv = 1.0f / sum;
#pragma unroll
        for (int nt = 0; nt < 4; nt++) {
          int j = nt * 16 + lrow;
          int addr = ((i * 64 + j) * 2) ^ ((i & 7) << 4);
          *(u16*)((char*)pw + addr) = f2bf(vals[nt] * inv);
        }
      }
    }
    asm volatile("s_waitcnt lgkmcnt(0)" ::: "memory");
    // PV: O[i][d] = sum_j P[i][j] * V[j][d] ; B-frag direct from vt (V transposed).
    // vt pad rows j=49..63 are never written -> mask to 0 in-register (call-1 garbage
    // could be NaN; 0*NaN would poison whole output columns).
    f32x4 o[4][2];
#pragma unroll
    for (int mt = 0; mt < 4; mt++)
#pragma unroll
      for (int nt = 0; nt < 2; nt++) o[mt][nt] = (f32x4){0.f, 0.f, 0.f, 0.f};
#pragma unroll
    for (int kt = 0; kt < 2; kt++) {
      bf16x8 pf[4], vf[2];
#pragma unroll
      for (int mt = 0; mt < 4; mt++) {
        int i = mt * 16 + lrow;
        int j = kt * 32 + kg * 8;
        int addr = ((i * 64 + j) * 2) ^ ((i & 7) << 4);
        pf[mt] = *(const bf16x8*)((const char*)pw + addr);
      }
#pragma unroll
      for (int nt = 0; nt < 2; nt++) {
        int d = nt * 16 + lrow;
        vf[nt] = *(const bf16x8*)(vt + ((size_t)(b * 12 + h) * 32 + d) * 64 + kt * 32 + kg * 8);
        if (kt == 1) {
          int j0 = 32 + kg * 8;
#pragma unroll
          for (int e = 0; e < 8; e++)
            if (j0 + e >= 49) vf[nt][e] = 0;
        }
      }
#pragma unroll
      for (int mt = 0; mt < 4; mt++)
#pragma unroll
        for (int nt = 0; nt < 2; nt++)
          o[mt][nt] = __builtin_amdgcn_mfma_f32_16x16x32_bf16(pf[mt], vf[nt], o[mt][nt], 0, 0, 0);
    }
#pragma unroll
    for (int mt = 0; mt < 4; mt++) {
#pragma unroll
      for (int nt = 0; nt < 2; nt++) {
#pragma unroll
        for (int r = 0; r < 4; r++) {
          int i = mt * 16 + kg * 4 + r;
          if (i < 49) {
            int d = nt * 16 + lrow;
            aout[((size_t)(b * 49 + i)) * 384 + h * 32 + d] = f2bf(o[mt][nt][r]);
          }
        }
      }
    }
  }
}

extern "C" void kernel_launch(void* const* d_in, const int* in_sizes, int n_in,
                              void* d_out, int out_size, void* d_ws, size_t ws_size,
                              hipStream_t stream) {
  const float* x = (const float*)d_in[0];
  const float* qkv_w = (const float*)d_in[1];
  const float* qkv_b = (const float*)d_in[2];
  const float* rp_table = (const float*)d_in[3];
  const float* out_w = (const float*)d_in[4];
  const float* out_b = (const float*)d_in[5];
  const int* rp_index = (const int*)d_in[6];
  const float* mask = (const float*)d_in[7];

  int Bwin = in_sizes[0] / (49 * 384);  // 4096
  int nW = in_sizes[7] / (49 * 49);     // 64
  int M = Bwin * 49;                    // 200704 (divisible by 128)

  char* ws = (char*)d_ws;
  u16* xb = (u16*)(ws);                      // 154,140,672 B (also reused as attn_out)
  u16* qkbuf = (u16*)(ws + 154140672);       // 308,281,344 B : [M][768] bf16
  u16* vtbuf = (u16*)(ws + 462422016);       // 201,326,592 B : [B*12*32][64] bf16
  u16* qkv_wp = (u16*)(ws + 663748608);      // 884,736 B
  float* qkv_bp = (float*)(ws + 664633344);  // 4,608 B
  u16* out_wb = (u16*)(ws + 664637952);      // 294,912 B
  float* bmbuf = (float*)(ws + 664932864);   // nW*12*49*64*4 = 9,633,792 B
  u16* attn_out = xb;                        // alias: xb dead after gemm1

  int n4 = in_sizes[0] / 4;
  cast_x_kernel<<<4096, 256, 0, stream>>>((const float4*)x, (ushort4*)xb, n4);
  prep_kernel<<<1184, 256, 0, stream>>>(qkv_w, qkv_b, out_w, qkv_wp, qkv_bp, out_wb);
  int bmtotal = nW * 12 * 49 * 64;
  bmask_kernel<<<(bmtotal + 255) / 256, 256, 0, stream>>>(rp_index, rp_table, mask, bmbuf, nW);
  gemm_bt<1><<<(M / 128) * 9, 256, 0, stream>>>(xb, qkv_wp, qkv_bp, qkbuf, vtbuf, nullptr, 384, 9);
  attn_kernel<<<Bwin, 256, 0, stream>>>(qkbuf, vtbuf, bmbuf, attn_out, nW);
  gemm_bt<2><<<(M / 128) * 3, 256, 0, stream>>>(attn_out, out_wb, out_b, nullptr, nullptr,
                                                (float*)d_out, 384, 3);
}